// Round 16
// baseline (47.376 us; speedup 1.0000x reference)
//
#include <hip/hip_runtime.h>

// LLR denoiser, two-phase, atomic-free:
//   Phase 1 (llr_zs): per patch p, S_p = alpha_p * Zhat_p (16x16 ~ THS*G^{-1/2})
//            via register-resident Newton-Schulz; bf16 to ws. XCD-swizzled.
//   Phase 2 (llr_cells): R16 — apply rebuilt in llr_zs's own (fast) idiom:
//            one wave = 4 cells; W via 10 coalesced zs loads summed in regs
//            (symmetric -> fragc A-operand); X loaded as MFMA B-fragment
//            (zs-style 16-plane scatter, max MLP/instr); ONE mfma per cell;
//            out = x - d in-lane (B-frag and C/D lane maps coincide);
//            4 scatter stores/cell. Zero LDS, zero barriers, <=64 VGPR,
//            32 waves/CU.

#define NBATCH  2
#define NCH     16
#define HDIM    512
#define WDIM    512
#define NPH     127
#define NPW     127
#define NPATCH  (NBATCH * NPH * NPW)
#define NCELL   128
#define THS     0.1f
#define NSIT    8

typedef short bf16x8 __attribute__((ext_vector_type(8)));
typedef float f32x4  __attribute__((ext_vector_type(4)));

#define MFMA(a,b,c) __builtin_amdgcn_mfma_f32_16x16x32_bf16((a),(b),(c),0,0,0)

static __device__ inline short f2bf(float x) {
  return __builtin_bit_cast(short, (__bf16)x);   // native RNE convert
}
static __device__ inline float blo2f(unsigned int v) {
  return __builtin_bit_cast(float, v << 16);
}
static __device__ inline float bhi2f(unsigned int v) {
  return __builtin_bit_cast(float, v & 0xffff0000u);
}
static __device__ inline unsigned int pack2bf(float lo, float hi) {
  unsigned int a = (unsigned short)f2bf(lo);
  unsigned int b = (unsigned short)f2bf(hi);
  return (b << 16) | a;
}

// bijective XCD swizzle (m204) — used by llr_zs only
static __device__ inline int xcd_swz(int b, int nwg) {
  const int q = nwg >> 3, r = nwg & 7;
  const int x = b & 7, lo = b >> 3;
  return (x < r ? x * (q + 1) : r * (q + 1) + (x - r) * q) + lo;
}

static __device__ inline bf16x8 fragc(f32x4 v) {
  // symmetric-matrix C-layout -> MFMA A/B fragment (16 nonzero k-slots)
  bf16x8 r;
  r[0] = f2bf(v[0]); r[1] = f2bf(v[1]); r[2] = f2bf(v[2]); r[3] = f2bf(v[3]);
  r[4] = 0; r[5] = 0; r[6] = 0; r[7] = 0;
  return r;
}

// ---------------- Phase 1: per-patch scaled inverse-sqrt matrices ----------
// 256 threads = 4 waves = 4 consecutive patches per block.
#define ZS_NBLK ((NPATCH + 3) / 4)
__global__ __launch_bounds__(256) void llr_zs(const float* __restrict__ x,
                                              uint2* __restrict__ zs) {
  const int blk = xcd_swz(blockIdx.x, ZS_NBLK);
  const int pid = blk * 4 + (threadIdx.x >> 6);  // one wave per patch
  if (pid >= NPATCH) return;
  const int bi  = pid / (NPH * NPW);
  const int pr  = pid % (NPH * NPW);
  const int ph  = pr / NPW, pw = pr % NPW;
  const int h0  = ph * 4, w0 = pw * 4;
  const int l   = threadIdx.x & 63;
  const int j   = l & 15;                      // row/col id in 16x16 tiles
  const int u   = l >> 4;                      // k-group 0..3

  const size_t HW = (size_t)HDIM * WDIM;
  const float* xb = x + (size_t)bi * NCH * HW;

  // load M (16 channels x 64 pixels) in A-frag layout
  const float* pb = xb + (size_t)j * HW + (size_t)h0 * WDIM + w0;
  const int dh0 = (u >> 1), dw0 = 4 * (u & 1);
  float4 q0 = *(const float4*)(pb + (size_t)(dh0 + 0) * WDIM + dw0);
  float4 q1 = *(const float4*)(pb + (size_t)(dh0 + 2) * WDIM + dw0);
  float4 q2 = *(const float4*)(pb + (size_t)(dh0 + 4) * WDIM + dw0);
  float4 q3 = *(const float4*)(pb + (size_t)(dh0 + 6) * WDIM + dw0);

  bf16x8 m0, m1;
  m0[0]=f2bf(q0.x); m0[1]=f2bf(q0.y); m0[2]=f2bf(q0.z); m0[3]=f2bf(q0.w);
  m0[4]=f2bf(q1.x); m0[5]=f2bf(q1.y); m0[6]=f2bf(q1.z); m0[7]=f2bf(q1.w);
  m1[0]=f2bf(q2.x); m1[1]=f2bf(q2.y); m1[2]=f2bf(q2.z); m1[3]=f2bf(q2.w);
  m1[4]=f2bf(q3.x); m1[5]=f2bf(q3.y); m1[6]=f2bf(q3.z); m1[7]=f2bf(q3.w);

  // G = M M^T
  f32x4 g = {0.f, 0.f, 0.f, 0.f};
  g = MFMA(m0, m0, g);
  g = MFMA(m1, m1, g);

  // Frobenius norm^2 of G
  float s2 = g[0]*g[0] + g[1]*g[1] + g[2]*g[2] + g[3]*g[3];
  #pragma unroll
  for (int m = 32; m >= 1; m >>= 1) s2 += __shfl_xor(s2, m, 64);

  uint2 wv = {0u, 0u};
  if (s2 > 1e-20f) {
    const float invf  = rsqrtf(s2);            // 1/f, f = ||G||_F >= lmax
    const float gsc   = 2.0f * invf;           // normalize by t = f/2 (eig in (0,2])
    const float alpha = THS * sqrtf(gsc);      // THS / sqrt(t)

    // coupled Newton-Schulz: Y0 = G/t, Z0 = I; Z -> (G/t)^{-1/2}
    f32x4 Yc, Zc;
    #pragma unroll
    for (int r = 0; r < 4; ++r) {
      Yc[r] = g[r] * gsc;
      Zc[r] = (4 * u + r == j) ? 1.0f : 0.0f;
    }

    const f32x4 zero = {0.f, 0.f, 0.f, 0.f};
    for (int it = 0; it < NSIT - 1; ++it) {
      bf16x8 yF = fragc(Yc), zF = fragc(Zc);
      f32x4 t  = MFMA(zF, yF, zero);           // T = Z*Y
      bf16x8 tF = fragc(t);
      f32x4 py = MFMA(yF, tF, zero);           // Y*T
      f32x4 pz = MFMA(tF, zF, zero);           // T*Z
      #pragma unroll
      for (int r = 0; r < 4; ++r) {
        Yc[r] = 1.5f * Yc[r] - 0.5f * py[r];
        Zc[r] = 1.5f * Zc[r] - 0.5f * pz[r];
      }
    }
    { // final iteration: only Z needed
      bf16x8 yF = fragc(Yc), zF = fragc(Zc);
      f32x4 t  = MFMA(zF, yF, zero);
      bf16x8 tF = fragc(t);
      f32x4 pz = MFMA(tF, zF, zero);
      #pragma unroll
      for (int r = 0; r < 4; ++r) Zc[r] = 1.5f * Zc[r] - 0.5f * pz[r];
    }

    wv.x = pack2bf(alpha * Zc[0], alpha * Zc[1]);
    wv.y = pack2bf(alpha * Zc[2], alpha * Zc[3]);
  }
  zs[(size_t)pid * 64 + l] = wv;               // coalesced 512B per patch
}

// ---------------- Phase 2: per-wave MFMA apply, zero LDS -------------------
// Block = 4 waves; wave w handles cells c0..c0+3 (c0 = wq*16 + w*4) of
// cell-row ci, batch bi. Lane (u = l>>4, j = l&15).
//   Gather: 5 patch cols (c0-1..c0+3) x 2 rows -> 10 coalesced uint2 loads,
//           clamped + zero-masked; held in registers.
//   Per cell c: W = sc * (s0[c]+s1[c]+s0[c+1]+s1[c+1])  (symmetric, f32 sum)
//               A-frag = fragc(W); B-frag: lane (u,j) reg e = x[ch 4u+e]
//               [px j of cell] (4 scatter dword loads);
//               d = MFMA(A,B,0): lane (u,j) reg e = (W x)[ch 4u+e][px j]
//               -> out = x - d elementwise in-lane; 4 scatter dword stores.
#define AP_NBLK (NBATCH * NCELL * 8)   // 2048
__global__ __launch_bounds__(256, 8) void llr_cells(const float* __restrict__ x,
                                                    const uint2* __restrict__ zs,
                                                    float* __restrict__ out) {
  const int bid = blockIdx.x;                  // bi*1024 + ci*8 + wq
  const int wq  = bid & 7;
  const int ci  = (bid >> 3) & 127;
  const int bi  = bid >> 10;
  const int t   = threadIdx.x;
  const int w   = t >> 6;                      // wave 0..3
  const int l   = t & 63;
  const int u   = l >> 4, j = l & 15;

  const size_t HW = (size_t)HDIM * WDIM;
  const int c0  = wq * 16 + w * 4;             // first cell col (0..124)
  const int row = 4 * ci + (j >> 2);           // pixel row for this lane

  // ---- gather 5 slots x 2 patch rows (coalesced 512B each), masked
  const uint2* zb = zs + (size_t)bi * NPH * NPW * 64;
  const bool vh0 = (ci > 0), vh1 = (ci < NPH);
  const int ph0c = vh0 ? ci - 1 : 0;
  const int ph1c = vh1 ? ci : 0;
  uint2 s0[5], s1[5];
  float vws[5];
  #pragma unroll
  for (int s = 0; s < 5; ++s) {
    const int pw = c0 - 1 + s;
    const bool v = ((unsigned)pw <= (unsigned)(NPW - 1));
    const int pwc = v ? pw : 0;
    uint2 a = zb[((size_t)ph0c * NPW + pwc) * 64 + l];
    uint2 b = zb[((size_t)ph1c * NPW + pwc) * 64 + l];
    if (!(v && vh0)) { a.x = 0u; a.y = 0u; }
    if (!(v && vh1)) { b.x = 0u; b.y = 0u; }
    s0[s] = a; s1[s] = b;
    vws[s] = v ? 1.0f : 0.0f;
  }
  const float cnth = 2.0f - (ci == 0) - (ci == NCELL - 1);

  // ---- per-lane base pointers (channel 4u, this lane's pixel row/col phase)
  const float* xbse = x + (size_t)bi * NCH * HW + (size_t)(4 * u) * HW
                        + (size_t)row * WDIM + 4 * c0 + (j & 3);
  float* obse = out + (size_t)bi * NCH * HW + (size_t)(4 * u) * HW
                    + (size_t)row * WDIM + 4 * c0 + (j & 3);
  const f32x4 zero = {0.f, 0.f, 0.f, 0.f};

  #pragma unroll
  for (int c = 0; c < 4; ++c) {
    // W = sc * sum of 4 covering S (unpack packed-bf16 pairs, f32 sum)
    const float cntw = vws[c] + vws[c + 1];
    const float sc = 1.0f / (cnth * cntw);
    f32x4 Wc;
    Wc[0] = sc * (blo2f(s0[c].x) + blo2f(s1[c].x) + blo2f(s0[c+1].x) + blo2f(s1[c+1].x));
    Wc[1] = sc * (bhi2f(s0[c].x) + bhi2f(s1[c].x) + bhi2f(s0[c+1].x) + bhi2f(s1[c+1].x));
    Wc[2] = sc * (blo2f(s0[c].y) + blo2f(s1[c].y) + blo2f(s0[c+1].y) + blo2f(s1[c+1].y));
    Wc[3] = sc * (bhi2f(s0[c].y) + bhi2f(s1[c].y) + bhi2f(s0[c+1].y) + bhi2f(s1[c+1].y));
    bf16x8 wF = fragc(Wc);

    // X fragment: 4 scatter dword loads (plane 4u+e, this lane's pixel)
    float xf0 = xbse[4 * c];
    float xf1 = xbse[4 * c + HW];
    float xf2 = xbse[4 * c + 2 * HW];
    float xf3 = xbse[4 * c + 3 * HW];
    bf16x8 xF;
    xF[0] = f2bf(xf0); xF[1] = f2bf(xf1); xF[2] = f2bf(xf2); xF[3] = f2bf(xf3);
    xF[4] = 0; xF[5] = 0; xF[6] = 0; xF[7] = 0;

    f32x4 d = MFMA(wF, xF, zero);              // d[e] = (W*X)[4u+e][px j]

    obse[4 * c]          = xf0 - d[0];
    obse[4 * c + HW]     = xf1 - d[1];
    obse[4 * c + 2 * HW] = xf2 - d[2];
    obse[4 * c + 3 * HW] = xf3 - d[3];
  }
}

extern "C" void kernel_launch(void* const* d_in, const int* in_sizes, int n_in,
                              void* d_out, int out_size, void* d_ws, size_t ws_size,
                              hipStream_t stream) {
  const float* x = (const float*)d_in[0];
  float* out = (float*)d_out;
  uint2* zs = (uint2*)d_ws;                    // 32258*512B = 16.5 MB

  llr_zs<<<dim3(ZS_NBLK), dim3(256), 0, stream>>>(x, zs);
  llr_cells<<<dim3(AP_NBLK), dim3(256), 0, stream>>>(x, zs, out);
}